// Round 1
// baseline (793.279 us; speedup 1.0000x reference)
//
#include <hip/hip_runtime.h>

#define B_    64
#define HID_  4096
#define HQ_   32
#define HKV_  8
#define D_    128
#define BS_   16
#define MAXB_ 64

#define KSPLIT  16
#define KCHUNK  (HID_ / KSPLIT)   // 256
#define QKV_ROWS 6144             // 4096 q + 1024 k + 1024 v
#define O_ROWS   4096

// workspace layout (floats)
#define PART1_SZ ((size_t)KSPLIT * QKV_ROWS * 64)
#define QKVF_SZ  ((size_t)64 * 6144)
#define ATTN_SZ  ((size_t)64 * 4096)
#define PART3_SZ ((size_t)KSPLIT * O_ROWS * 64)

// ---------------------------------------------------------------------------
// Skinny GEMM partial: out rows = W rows (256 per block), 64 batches.
// part[ksplit][row][batch] += X[batch,:] . W[row,:] over this block's K-chunk
// ---------------------------------------------------------------------------
__global__ __launch_bounds__(256) void gemm_part(
    const float* __restrict__ X, const float* __restrict__ W0,
    const float* __restrict__ W1, const float* __restrict__ W2,
    int split1, int split2, int rows_total, float* __restrict__ part)
{
  __shared__ float wt[256][36];   // stride 36 floats = 9 x 16B chunks (odd) -> conflict-free b128
  __shared__ float ht[64][36];

  const int tid = threadIdx.x;
  const int r0  = blockIdx.x * 256;
  const int k0  = blockIdx.y * KCHUNK;

  const float* W; int rloc;
  if (r0 < split1)      { W = W0; rloc = r0; }
  else if (r0 < split2) { W = W1; rloc = r0 - split1; }
  else                  { W = W2; rloc = r0 - split2; }

  float acc[8][8];
  #pragma unroll
  for (int i = 0; i < 8; ++i)
    #pragma unroll
    for (int j = 0; j < 8; ++j) acc[i][j] = 0.f;

  const int c4 = (tid & 7) * 4;   // k offset within 32-wide step
  const int rs = tid >> 3;        // 0..31
  const int tx = tid & 7;         // batch group
  const int ty = tid >> 3;        // row group

  for (int ks = 0; ks < KCHUNK; ks += 32) {
    #pragma unroll
    for (int p = 0; p < 8; ++p) {
      int rr = rs + 32 * p;
      float4 w = *(const float4*)(W + (size_t)(rloc + rr) * HID_ + (k0 + ks + c4));
      *(float4*)&wt[rr][c4] = w;
    }
    #pragma unroll
    for (int p = 0; p < 2; ++p) {
      int bb = rs + 32 * p;
      float4 x = *(const float4*)(X + (size_t)bb * HID_ + (k0 + ks + c4));
      *(float4*)&ht[bb][c4] = x;
    }
    __syncthreads();
    #pragma unroll
    for (int kk = 0; kk < 32; kk += 4) {
      float4 hreg[8];
      #pragma unroll
      for (int j = 0; j < 8; ++j) hreg[j] = *(float4*)&ht[tx + 8 * j][kk];
      #pragma unroll
      for (int i = 0; i < 8; ++i) {
        float4 w = *(float4*)&wt[ty + 32 * i][kk];
        #pragma unroll
        for (int j = 0; j < 8; ++j)
          acc[i][j] += w.x * hreg[j].x + w.y * hreg[j].y + w.z * hreg[j].z + w.w * hreg[j].w;
      }
    }
    __syncthreads();
  }

  float* base = part + (size_t)blockIdx.y * rows_total * 64;
  #pragma unroll
  for (int i = 0; i < 8; ++i) {
    int r = r0 + ty + 32 * i;
    #pragma unroll
    for (int j = 0; j < 8; ++j)
      base[(size_t)r * 64 + tx + 8 * j] = acc[i][j];
  }
}

// ---------------------------------------------------------------------------
// Sum K-split partials + RoPE (half-split). q scaled by 1/sqrt(D).
// qkvf layout: q[64][32][128] | k[64][8][128] | v[64][8][128]
// ---------------------------------------------------------------------------
__global__ __launch_bounds__(256) void reduce_rope(
    const float* __restrict__ part, const float* __restrict__ cosT,
    const float* __restrict__ sinT, const int* __restrict__ positions,
    float* __restrict__ qkvf)
{
  const int bb  = threadIdx.x & 63;
  const int cid = blockIdx.x * 4 + (threadIdx.x >> 6);  // 0..3071
  const int pos = positions[bb];

  if (cid < 2048) {                       // q pairs: (hq, d0)
    const int hq = cid >> 6, d0 = cid & 63;
    const int r1 = hq * 128 + d0;
    float x1 = 0.f, x2 = 0.f;
    #pragma unroll
    for (int ks = 0; ks < KSPLIT; ++ks) {
      x1 += part[((size_t)ks * QKV_ROWS + r1) * 64 + bb];
      x2 += part[((size_t)ks * QKV_ROWS + r1 + 64) * 64 + bb];
    }
    float c = cosT[pos * 64 + d0], s = sinT[pos * 64 + d0];
    const float scale = 0.08838834764831843f;   // 1/sqrt(128)
    qkvf[(size_t)(bb * 32 + hq) * 128 + d0]      = (x1 * c - x2 * s) * scale;
    qkvf[(size_t)(bb * 32 + hq) * 128 + d0 + 64] = (x2 * c + x1 * s) * scale;
  } else if (cid < 2560) {                // k pairs
    const int c2 = cid - 2048;
    const int kh = c2 >> 6, d0 = c2 & 63;
    const int r1 = 4096 + kh * 128 + d0;
    float x1 = 0.f, x2 = 0.f;
    #pragma unroll
    for (int ks = 0; ks < KSPLIT; ++ks) {
      x1 += part[((size_t)ks * QKV_ROWS + r1) * 64 + bb];
      x2 += part[((size_t)ks * QKV_ROWS + r1 + 64) * 64 + bb];
    }
    float c = cosT[pos * 64 + d0], s = sinT[pos * 64 + d0];
    qkvf[262144 + (size_t)(bb * 8 + kh) * 128 + d0]      = x1 * c - x2 * s;
    qkvf[262144 + (size_t)(bb * 8 + kh) * 128 + d0 + 64] = x2 * c + x1 * s;
  } else {                                // v passthrough
    const int c2 = cid - 2560;
    const int kh = c2 >> 6, d0 = c2 & 63;
    const int r1 = 5120 + kh * 128 + d0;
    float x1 = 0.f, x2 = 0.f;
    #pragma unroll
    for (int ks = 0; ks < KSPLIT; ++ks) {
      x1 += part[((size_t)ks * QKV_ROWS + r1) * 64 + bb];
      x2 += part[((size_t)ks * QKV_ROWS + r1 + 64) * 64 + bb];
    }
    qkvf[327680 + (size_t)(bb * 8 + kh) * 128 + d0]      = x1;
    qkvf[327680 + (size_t)(bb * 8 + kh) * 128 + d0 + 64] = x2;
  }
}

// ---------------------------------------------------------------------------
// Decode attention: one block per (seq b, kv-head h). 8 half-waves, 32 lanes
// each own one token at a time (coalesced 512B K/V row strips).
// Token t == ctx-1 uses freshly computed roped k / v (virtual cache scatter).
// ---------------------------------------------------------------------------
__global__ __launch_bounds__(256) void attn_kernel(
    const float* __restrict__ qkvf, const float* __restrict__ kcache,
    const float* __restrict__ vcache, const int* __restrict__ btab,
    const int* __restrict__ ctxlen, float* __restrict__ attn_out)
{
  const int b = blockIdx.x >> 3, h = blockIdx.x & 7;
  const int tid  = threadIdx.x;
  const int half = tid >> 5;     // 0..7
  const int d4   = tid & 31;     // float4 index within 128-dim row
  const int ctx  = ctxlen[b];
  const int last = ctx - 1;

  __shared__ float sc[4][1024];
  __shared__ float oacc[8][4][128];
  __shared__ float ssum[4];

  float4 qf[4];
  #pragma unroll
  for (int g = 0; g < 4; ++g)
    qf[g] = *(const float4*)(qkvf + (size_t)(b * 32 + h * 4 + g) * 128 + d4 * 4);

  const float* knew = qkvf + 262144 + (size_t)(b * 8 + h) * 128;
  const float* vnew = qkvf + 327680 + (size_t)(b * 8 + h) * 128;

  // ---- pass 1: scores
  for (int t = half; t < ctx; t += 8) {
    const float* kp;
    if (t == last) kp = knew;
    else {
      int slot = btab[b * MAXB_ + (t >> 4)] * BS_ + (t & 15);
      kp = kcache + ((size_t)slot * HKV_ + h) * D_;
    }
    float4 kv = *(const float4*)(kp + d4 * 4);
    float p0 = qf[0].x * kv.x + qf[0].y * kv.y + qf[0].z * kv.z + qf[0].w * kv.w;
    float p1 = qf[1].x * kv.x + qf[1].y * kv.y + qf[1].z * kv.z + qf[1].w * kv.w;
    float p2 = qf[2].x * kv.x + qf[2].y * kv.y + qf[2].z * kv.z + qf[2].w * kv.w;
    float p3 = qf[3].x * kv.x + qf[3].y * kv.y + qf[3].z * kv.z + qf[3].w * kv.w;
    #pragma unroll
    for (int m = 16; m >= 1; m >>= 1) {
      p0 += __shfl_xor(p0, m);
      p1 += __shfl_xor(p1, m);
      p2 += __shfl_xor(p2, m);
      p3 += __shfl_xor(p3, m);
    }
    if (d4 == 0) { sc[0][t] = p0; sc[1][t] = p1; sc[2][t] = p2; sc[3][t] = p3; }
  }
  __syncthreads();

  // ---- softmax: wave w handles group-head g = w
  {
    const int w = tid >> 6, l = tid & 63;
    float mx = -1e30f;
    for (int t = l; t < ctx; t += 64) mx = fmaxf(mx, sc[w][t]);
    #pragma unroll
    for (int m = 32; m >= 1; m >>= 1) mx = fmaxf(mx, __shfl_xor(mx, m));
    float lsum = 0.f;
    for (int t = l; t < ctx; t += 64) {
      float p = __expf(sc[w][t] - mx);
      sc[w][t] = p;
      lsum += p;
    }
    #pragma unroll
    for (int m = 32; m >= 1; m >>= 1) lsum += __shfl_xor(lsum, m);
    if (l == 0) ssum[w] = lsum;
  }
  __syncthreads();

  // ---- pass 2: P.V
  float acc[4][4] = {{0.f}};
  for (int t = half; t < ctx; t += 8) {
    const float* vp;
    if (t == last) vp = vnew;
    else {
      int slot = btab[b * MAXB_ + (t >> 4)] * BS_ + (t & 15);
      vp = vcache + ((size_t)slot * HKV_ + h) * D_;
    }
    float4 vv = *(const float4*)(vp + d4 * 4);
    #pragma unroll
    for (int g = 0; g < 4; ++g) {
      float p = sc[g][t];
      acc[g][0] += p * vv.x; acc[g][1] += p * vv.y;
      acc[g][2] += p * vv.z; acc[g][3] += p * vv.w;
    }
  }
  #pragma unroll
  for (int g = 0; g < 4; ++g) {
    float inv = 1.f / ssum[g];
    #pragma unroll
    for (int j = 0; j < 4; ++j)
      oacc[half][g][d4 * 4 + j] = acc[g][j] * inv;
  }
  __syncthreads();

  for (int idx = tid; idx < 512; idx += 256) {
    int g = idx >> 7, d = idx & 127;
    float s = 0.f;
    #pragma unroll
    for (int hh = 0; hh < 8; ++hh) s += oacc[hh][g][d];
    attn_out[(size_t)(b * 32 + h * 4 + g) * 128 + d] = s;
  }
}

// ---------------------------------------------------------------------------
__global__ __launch_bounds__(256) void reduce_out(
    const float* __restrict__ part, float* __restrict__ out)
{
  int o  = blockIdx.x * 256 + threadIdx.x;  // 0..262143
  int bb = o >> 12, i = o & 4095;
  float s = 0.f;
  #pragma unroll
  for (int ks = 0; ks < KSPLIT; ++ks)
    s += part[((size_t)ks * O_ROWS + i) * 64 + bb];
  out[o] = s;
}

// ---------------------------------------------------------------------------
extern "C" void kernel_launch(void* const* d_in, const int* in_sizes, int n_in,
                              void* d_out, int out_size, void* d_ws, size_t ws_size,
                              hipStream_t stream)
{
  (void)in_sizes; (void)n_in; (void)out_size; (void)ws_size;
  const float* hidden    = (const float*)d_in[0];
  const int*   positions = (const int*)d_in[1];
  const float* cosT      = (const float*)d_in[2];
  const float* sinT      = (const float*)d_in[3];
  const float* kcache    = (const float*)d_in[4];
  const float* vcache    = (const float*)d_in[5];
  // d_in[6] slot_mapping: implied by block_tables/context_lens for this layout
  const int*   btab      = (const int*)d_in[7];
  const int*   ctx       = (const int*)d_in[8];
  const float* Wq        = (const float*)d_in[9];
  const float* Wk        = (const float*)d_in[10];
  const float* Wv        = (const float*)d_in[11];
  const float* Wo        = (const float*)d_in[12];
  float* out = (float*)d_out;

  float* ws     = (float*)d_ws;
  float* part1  = ws;
  float* qkvf   = part1 + PART1_SZ;
  float* attn_o = qkvf + QKVF_SZ;
  float* part3  = attn_o + ATTN_SZ;

  gemm_part<<<dim3(QKV_ROWS / 256, KSPLIT), 256, 0, stream>>>(
      hidden, Wq, Wk, Wv, 4096, 5120, QKV_ROWS, part1);
  reduce_rope<<<768, 256, 0, stream>>>(part1, cosT, sinT, positions, qkvf);
  attn_kernel<<<B_ * HKV_, 256, 0, stream>>>(qkvf, kcache, vcache, btab, ctx, attn_o);
  gemm_part<<<dim3(O_ROWS / 256, KSPLIT), 256, 0, stream>>>(
      attn_o, Wo, Wo, Wo, O_ROWS, O_ROWS, O_ROWS, part3);
  reduce_out<<<1024, 256, 0, stream>>>(part3, out);
}

// Round 2
// 624.130 us; speedup vs baseline: 1.2710x; 1.2710x over previous
//
#include <hip/hip_runtime.h>

#define B_    64
#define HID_  4096
#define HQ_   32
#define HKV_  8
#define D_    128
#define BS_   16
#define MAXB_ 64

#define KSPLIT  16
#define KCHUNK  (HID_ / KSPLIT)   // 256
#define QKV_ROWS 6144             // 4096 q + 1024 k + 1024 v
#define O_ROWS   4096
#define RPB     128               // rows per block in gemm_part

// workspace layout (floats)
#define PART1_SZ ((size_t)KSPLIT * QKV_ROWS * 64)
#define QKVF_SZ  ((size_t)64 * 6144)
#define ATTN_SZ  ((size_t)64 * 4096)
#define PART3_SZ ((size_t)KSPLIT * O_ROWS * 64)

// ---------------------------------------------------------------------------
// Register-streaming skinny GEMM partial. No LDS, no barriers.
// Thread (tx,ty): tx=0..7 owns batches 8tx..8tx+7; ty=0..31 owns rows
// r0+4ty..+3. W streams global->reg (8 duplicate lanes merge in TA);
// X rows broadcast via L1/L2. part[ksplit][row][batch].
// ---------------------------------------------------------------------------
__global__ __launch_bounds__(256, 2) void gemm_part(
    const float* __restrict__ X, const float* __restrict__ W0,
    const float* __restrict__ W1, const float* __restrict__ W2,
    int split1, int split2, int rows_total, float* __restrict__ part)
{
  const int tid = threadIdx.x;
  const int tx  = tid & 7;
  const int ty  = tid >> 3;
  const int r0  = blockIdx.x * RPB;
  const int k0  = blockIdx.y * KCHUNK;

  const float* W; int rloc;
  if (r0 < split1)      { W = W0; rloc = r0; }
  else if (r0 < split2) { W = W1; rloc = r0 - split1; }
  else                  { W = W2; rloc = r0 - split2; }

  const float* wrow = W + (size_t)(rloc + 4 * ty) * HID_ + k0;
  const float* xrow = X + (size_t)(8 * tx) * HID_ + k0;

  float acc[4][8];
  #pragma unroll
  for (int i = 0; i < 4; ++i)
    #pragma unroll
    for (int j = 0; j < 8; ++j) acc[i][j] = 0.f;

  #pragma unroll 2
  for (int k = 0; k < KCHUNK; k += 4) {
    float4 wv[4], xv[8];
    #pragma unroll
    for (int i = 0; i < 4; ++i)
      wv[i] = *(const float4*)(wrow + (size_t)i * HID_ + k);
    #pragma unroll
    for (int j = 0; j < 8; ++j)
      xv[j] = *(const float4*)(xrow + (size_t)j * HID_ + k);
    #pragma unroll
    for (int i = 0; i < 4; ++i)
      #pragma unroll
      for (int j = 0; j < 8; ++j)
        acc[i][j] += wv[i].x * xv[j].x + wv[i].y * xv[j].y
                   + wv[i].z * xv[j].z + wv[i].w * xv[j].w;
  }

  float* base = part + ((size_t)blockIdx.y * rows_total + r0 + 4 * ty) * 64 + 8 * tx;
  #pragma unroll
  for (int i = 0; i < 4; ++i) {
    float4 lo = make_float4(acc[i][0], acc[i][1], acc[i][2], acc[i][3]);
    float4 hi = make_float4(acc[i][4], acc[i][5], acc[i][6], acc[i][7]);
    *(float4*)(base + (size_t)i * 64)     = lo;
    *(float4*)(base + (size_t)i * 64 + 4) = hi;
  }
}

// ---------------------------------------------------------------------------
// Sum K-split partials + RoPE (half-split). q scaled by 1/sqrt(D).
// qkvf layout: q[64][32][128] | k[64][8][128] | v[64][8][128]
// ---------------------------------------------------------------------------
__global__ __launch_bounds__(256) void reduce_rope(
    const float* __restrict__ part, const float* __restrict__ cosT,
    const float* __restrict__ sinT, const int* __restrict__ positions,
    float* __restrict__ qkvf)
{
  const int bb  = threadIdx.x & 63;
  const int cid = blockIdx.x * 4 + (threadIdx.x >> 6);  // 0..3071
  const int pos = positions[bb];

  if (cid < 2048) {                       // q pairs: (hq, d0)
    const int hq = cid >> 6, d0 = cid & 63;
    const int r1 = hq * 128 + d0;
    float x1 = 0.f, x2 = 0.f;
    #pragma unroll
    for (int ks = 0; ks < KSPLIT; ++ks) {
      x1 += part[((size_t)ks * QKV_ROWS + r1) * 64 + bb];
      x2 += part[((size_t)ks * QKV_ROWS + r1 + 64) * 64 + bb];
    }
    float c = cosT[pos * 64 + d0], s = sinT[pos * 64 + d0];
    const float scale = 0.08838834764831843f;   // 1/sqrt(128)
    qkvf[(size_t)(bb * 32 + hq) * 128 + d0]      = (x1 * c - x2 * s) * scale;
    qkvf[(size_t)(bb * 32 + hq) * 128 + d0 + 64] = (x2 * c + x1 * s) * scale;
  } else if (cid < 2560) {                // k pairs
    const int c2 = cid - 2048;
    const int kh = c2 >> 6, d0 = c2 & 63;
    const int r1 = 4096 + kh * 128 + d0;
    float x1 = 0.f, x2 = 0.f;
    #pragma unroll
    for (int ks = 0; ks < KSPLIT; ++ks) {
      x1 += part[((size_t)ks * QKV_ROWS + r1) * 64 + bb];
      x2 += part[((size_t)ks * QKV_ROWS + r1 + 64) * 64 + bb];
    }
    float c = cosT[pos * 64 + d0], s = sinT[pos * 64 + d0];
    qkvf[262144 + (size_t)(bb * 8 + kh) * 128 + d0]      = x1 * c - x2 * s;
    qkvf[262144 + (size_t)(bb * 8 + kh) * 128 + d0 + 64] = x2 * c + x1 * s;
  } else {                                // v passthrough
    const int c2 = cid - 2560;
    const int kh = c2 >> 6, d0 = c2 & 63;
    const int r1 = 5120 + kh * 128 + d0;
    float x1 = 0.f, x2 = 0.f;
    #pragma unroll
    for (int ks = 0; ks < KSPLIT; ++ks) {
      x1 += part[((size_t)ks * QKV_ROWS + r1) * 64 + bb];
      x2 += part[((size_t)ks * QKV_ROWS + r1 + 64) * 64 + bb];
    }
    qkvf[327680 + (size_t)(bb * 8 + kh) * 128 + d0]      = x1;
    qkvf[327680 + (size_t)(bb * 8 + kh) * 128 + d0 + 64] = x2;
  }
}

// ---------------------------------------------------------------------------
// Decode attention: one block per (seq b, kv-head h). 8 half-waves, 32 lanes
// each own one token at a time (coalesced 512B K/V row strips).
// Token t == ctx-1 uses freshly computed roped k / v (virtual cache scatter).
// ---------------------------------------------------------------------------
__global__ __launch_bounds__(256) void attn_kernel(
    const float* __restrict__ qkvf, const float* __restrict__ kcache,
    const float* __restrict__ vcache, const int* __restrict__ btab,
    const int* __restrict__ ctxlen, float* __restrict__ attn_out)
{
  const int b = blockIdx.x >> 3, h = blockIdx.x & 7;
  const int tid  = threadIdx.x;
  const int half = tid >> 5;     // 0..7
  const int d4   = tid & 31;     // float4 index within 128-dim row
  const int ctx  = ctxlen[b];
  const int last = ctx - 1;

  __shared__ float sc[4][1024];
  __shared__ float oacc[8][4][128];
  __shared__ float ssum[4];

  float4 qf[4];
  #pragma unroll
  for (int g = 0; g < 4; ++g)
    qf[g] = *(const float4*)(qkvf + (size_t)(b * 32 + h * 4 + g) * 128 + d4 * 4);

  const float* knew = qkvf + 262144 + (size_t)(b * 8 + h) * 128;
  const float* vnew = qkvf + 327680 + (size_t)(b * 8 + h) * 128;

  // ---- pass 1: scores
  for (int t = half; t < ctx; t += 8) {
    const float* kp;
    if (t == last) kp = knew;
    else {
      int slot = btab[b * MAXB_ + (t >> 4)] * BS_ + (t & 15);
      kp = kcache + ((size_t)slot * HKV_ + h) * D_;
    }
    float4 kv = *(const float4*)(kp + d4 * 4);
    float p0 = qf[0].x * kv.x + qf[0].y * kv.y + qf[0].z * kv.z + qf[0].w * kv.w;
    float p1 = qf[1].x * kv.x + qf[1].y * kv.y + qf[1].z * kv.z + qf[1].w * kv.w;
    float p2 = qf[2].x * kv.x + qf[2].y * kv.y + qf[2].z * kv.z + qf[2].w * kv.w;
    float p3 = qf[3].x * kv.x + qf[3].y * kv.y + qf[3].z * kv.z + qf[3].w * kv.w;
    #pragma unroll
    for (int m = 16; m >= 1; m >>= 1) {
      p0 += __shfl_xor(p0, m);
      p1 += __shfl_xor(p1, m);
      p2 += __shfl_xor(p2, m);
      p3 += __shfl_xor(p3, m);
    }
    if (d4 == 0) { sc[0][t] = p0; sc[1][t] = p1; sc[2][t] = p2; sc[3][t] = p3; }
  }
  __syncthreads();

  // ---- softmax: wave w handles group-head g = w
  {
    const int w = tid >> 6, l = tid & 63;
    float mx = -1e30f;
    for (int t = l; t < ctx; t += 64) mx = fmaxf(mx, sc[w][t]);
    #pragma unroll
    for (int m = 32; m >= 1; m >>= 1) mx = fmaxf(mx, __shfl_xor(mx, m));
    float lsum = 0.f;
    for (int t = l; t < ctx; t += 64) {
      float p = __expf(sc[w][t] - mx);
      sc[w][t] = p;
      lsum += p;
    }
    #pragma unroll
    for (int m = 32; m >= 1; m >>= 1) lsum += __shfl_xor(lsum, m);
    if (l == 0) ssum[w] = lsum;
  }
  __syncthreads();

  // ---- pass 2: P.V
  float acc[4][4] = {{0.f}};
  for (int t = half; t < ctx; t += 8) {
    const float* vp;
    if (t == last) vp = vnew;
    else {
      int slot = btab[b * MAXB_ + (t >> 4)] * BS_ + (t & 15);
      vp = vcache + ((size_t)slot * HKV_ + h) * D_;
    }
    float4 vv = *(const float4*)(vp + d4 * 4);
    #pragma unroll
    for (int g = 0; g < 4; ++g) {
      float p = sc[g][t];
      acc[g][0] += p * vv.x; acc[g][1] += p * vv.y;
      acc[g][2] += p * vv.z; acc[g][3] += p * vv.w;
    }
  }
  #pragma unroll
  for (int g = 0; g < 4; ++g) {
    float inv = 1.f / ssum[g];
    #pragma unroll
    for (int j = 0; j < 4; ++j)
      oacc[half][g][d4 * 4 + j] = acc[g][j] * inv;
  }
  __syncthreads();

  for (int idx = tid; idx < 512; idx += 256) {
    int g = idx >> 7, d = idx & 127;
    float s = 0.f;
    #pragma unroll
    for (int hh = 0; hh < 8; ++hh) s += oacc[hh][g][d];
    attn_out[(size_t)(b * 32 + h * 4 + g) * 128 + d] = s;
  }
}

// ---------------------------------------------------------------------------
__global__ __launch_bounds__(256) void reduce_out(
    const float* __restrict__ part, float* __restrict__ out)
{
  int o  = blockIdx.x * 256 + threadIdx.x;  // 0..262143
  int bb = o >> 12, i = o & 4095;
  float s = 0.f;
  #pragma unroll
  for (int ks = 0; ks < KSPLIT; ++ks)
    s += part[((size_t)ks * O_ROWS + i) * 64 + bb];
  out[o] = s;
}

// ---------------------------------------------------------------------------
extern "C" void kernel_launch(void* const* d_in, const int* in_sizes, int n_in,
                              void* d_out, int out_size, void* d_ws, size_t ws_size,
                              hipStream_t stream)
{
  (void)in_sizes; (void)n_in; (void)out_size; (void)ws_size;
  const float* hidden    = (const float*)d_in[0];
  const int*   positions = (const int*)d_in[1];
  const float* cosT      = (const float*)d_in[2];
  const float* sinT      = (const float*)d_in[3];
  const float* kcache    = (const float*)d_in[4];
  const float* vcache    = (const float*)d_in[5];
  // d_in[6] slot_mapping: implied by block_tables/context_lens for this layout
  const int*   btab      = (const int*)d_in[7];
  const int*   ctx       = (const int*)d_in[8];
  const float* Wq        = (const float*)d_in[9];
  const float* Wk        = (const float*)d_in[10];
  const float* Wv        = (const float*)d_in[11];
  const float* Wo        = (const float*)d_in[12];
  float* out = (float*)d_out;

  float* ws     = (float*)d_ws;
  float* part1  = ws;
  float* qkvf   = part1 + PART1_SZ;
  float* attn_o = qkvf + QKVF_SZ;
  float* part3  = attn_o + ATTN_SZ;

  gemm_part<<<dim3(QKV_ROWS / RPB, KSPLIT), 256, 0, stream>>>(
      hidden, Wq, Wk, Wv, 4096, 5120, QKV_ROWS, part1);
  reduce_rope<<<768, 256, 0, stream>>>(part1, cosT, sinT, positions, qkvf);
  attn_kernel<<<B_ * HKV_, 256, 0, stream>>>(qkvf, kcache, vcache, btab, ctx, attn_o);
  gemm_part<<<dim3(O_ROWS / RPB, KSPLIT), 256, 0, stream>>>(
      attn_o, Wo, Wo, Wo, O_ROWS, O_ROWS, O_ROWS, part3);
  reduce_out<<<1024, 256, 0, stream>>>(part3, out);
}

// Round 3
// 488.106 us; speedup vs baseline: 1.6252x; 1.2787x over previous
//
#include <hip/hip_runtime.h>

#define B_    64
#define HID_  4096
#define HQ_   32
#define HKV_  8
#define D_    128
#define BS_   16
#define MAXB_ 64

#define KSPLIT  8
#define KCHUNK  (HID_ / KSPLIT)   // 512
#define QKV_ROWS 6144             // 4096 q + 1024 k + 1024 v
#define O_ROWS   4096
#define RPB     64                // rows per block in gemm_part
#define SPLITS  8                 // flash-decode token splits

// workspace layout (floats)
#define PART1_SZ ((size_t)KSPLIT * QKV_ROWS * 64)   // 3.1M floats
#define QKVF_SZ  ((size_t)64 * 6144)
#define ATTN_SZ  ((size_t)64 * 4096)
#define PART3_SZ ((size_t)KSPLIT * 64 * O_ROWS)

// ---------------------------------------------------------------------------
// Register-streaming skinny GEMM partial. No LDS, no barriers.
// tx=tid&15 owns batches 4tx..4tx+3; ty=tid>>4 owns rows r0+4ty..+3.
// bm=0: part[ks][row][64batch]   (QKV path, feeds reduce_rope)
// bm=1: part[ks][batch][rows]    (O path, feeds coalesced reduce_out)
// ---------------------------------------------------------------------------
__global__ __launch_bounds__(256, 4) void gemm_part(
    const float* __restrict__ X, const float* __restrict__ W0,
    const float* __restrict__ W1, const float* __restrict__ W2,
    int split1, int split2, int rows_total, int bm, float* __restrict__ part)
{
  const int tid = threadIdx.x;
  const int tx  = tid & 15;
  const int ty  = tid >> 4;
  const int r0  = blockIdx.x * RPB;
  const int k0  = blockIdx.y * KCHUNK;

  const float* W; int rloc;
  if (r0 < split1)      { W = W0; rloc = r0; }
  else if (r0 < split2) { W = W1; rloc = r0 - split1; }
  else                  { W = W2; rloc = r0 - split2; }

  const float* wrow = W + (size_t)(rloc + 4 * ty) * HID_ + k0;
  const float* xrow = X + (size_t)(4 * tx) * HID_ + k0;

  float acc[4][4];
  #pragma unroll
  for (int i = 0; i < 4; ++i)
    #pragma unroll
    for (int j = 0; j < 4; ++j) acc[i][j] = 0.f;

  #pragma unroll 2
  for (int k = 0; k < KCHUNK; k += 4) {
    float4 wv[4], xv[4];
    #pragma unroll
    for (int i = 0; i < 4; ++i)
      wv[i] = *(const float4*)(wrow + (size_t)i * HID_ + k);
    #pragma unroll
    for (int j = 0; j < 4; ++j)
      xv[j] = *(const float4*)(xrow + (size_t)j * HID_ + k);
    #pragma unroll
    for (int i = 0; i < 4; ++i)
      #pragma unroll
      for (int j = 0; j < 4; ++j)
        acc[i][j] += wv[i].x * xv[j].x + wv[i].y * xv[j].y
                   + wv[i].z * xv[j].z + wv[i].w * xv[j].w;
  }

  if (!bm) {
    float* base = part + ((size_t)blockIdx.y * rows_total + r0 + 4 * ty) * 64 + 4 * tx;
    #pragma unroll
    for (int i = 0; i < 4; ++i)
      *(float4*)(base + (size_t)i * 64) =
          make_float4(acc[i][0], acc[i][1], acc[i][2], acc[i][3]);
  } else {
    float* base = part + ((size_t)blockIdx.y * 64 + 4 * tx) * rows_total + r0 + 4 * ty;
    #pragma unroll
    for (int j = 0; j < 4; ++j)
      *(float4*)(base + (size_t)j * rows_total) =
          make_float4(acc[0][j], acc[1][j], acc[2][j], acc[3][j]);
  }
}

// ---------------------------------------------------------------------------
// Sum K-split partials + RoPE (half-split). q scaled by 1/sqrt(D).
// qkvf layout: q[64][32][128] | k[64][8][128] | v[64][8][128]
// ---------------------------------------------------------------------------
__global__ __launch_bounds__(256) void reduce_rope(
    const float* __restrict__ part, const float* __restrict__ cosT,
    const float* __restrict__ sinT, const int* __restrict__ positions,
    float* __restrict__ qkvf)
{
  const int bb  = threadIdx.x & 63;
  const int cid = blockIdx.x * 4 + (threadIdx.x >> 6);  // 0..3071
  const int pos = positions[bb];

  if (cid < 2048) {                       // q pairs: (hq, d0)
    const int hq = cid >> 6, d0 = cid & 63;
    const int r1 = hq * 128 + d0;
    float x1 = 0.f, x2 = 0.f;
    #pragma unroll
    for (int ks = 0; ks < KSPLIT; ++ks) {
      x1 += part[((size_t)ks * QKV_ROWS + r1) * 64 + bb];
      x2 += part[((size_t)ks * QKV_ROWS + r1 + 64) * 64 + bb];
    }
    float c = cosT[pos * 64 + d0], s = sinT[pos * 64 + d0];
    const float scale = 0.08838834764831843f;   // 1/sqrt(128)
    qkvf[(size_t)(bb * 32 + hq) * 128 + d0]      = (x1 * c - x2 * s) * scale;
    qkvf[(size_t)(bb * 32 + hq) * 128 + d0 + 64] = (x2 * c + x1 * s) * scale;
  } else if (cid < 2560) {                // k pairs
    const int c2 = cid - 2048;
    const int kh = c2 >> 6, d0 = c2 & 63;
    const int r1 = 4096 + kh * 128 + d0;
    float x1 = 0.f, x2 = 0.f;
    #pragma unroll
    for (int ks = 0; ks < KSPLIT; ++ks) {
      x1 += part[((size_t)ks * QKV_ROWS + r1) * 64 + bb];
      x2 += part[((size_t)ks * QKV_ROWS + r1 + 64) * 64 + bb];
    }
    float c = cosT[pos * 64 + d0], s = sinT[pos * 64 + d0];
    qkvf[262144 + (size_t)(bb * 8 + kh) * 128 + d0]      = x1 * c - x2 * s;
    qkvf[262144 + (size_t)(bb * 8 + kh) * 128 + d0 + 64] = x2 * c + x1 * s;
  } else {                                // v passthrough
    const int c2 = cid - 2560;
    const int kh = c2 >> 6, d0 = c2 & 63;
    const int r1 = 5120 + kh * 128 + d0;
    float x1 = 0.f, x2 = 0.f;
    #pragma unroll
    for (int ks = 0; ks < KSPLIT; ++ks) {
      x1 += part[((size_t)ks * QKV_ROWS + r1) * 64 + bb];
      x2 += part[((size_t)ks * QKV_ROWS + r1 + 64) * 64 + bb];
    }
    qkvf[327680 + (size_t)(bb * 8 + kh) * 128 + d0]      = x1;
    qkvf[327680 + (size_t)(bb * 8 + kh) * 128 + d0 + 64] = x2;
  }
}

// ---------------------------------------------------------------------------
// Flash-decode split attention: block = (b, h, split s). Each split handles
// chunk = ceil(ctx/8) tokens, emits unnormalized partial (m, l, sum pV).
// Token t == ctx-1 substitutes freshly-roped k/v (virtual cache scatter).
// ---------------------------------------------------------------------------
__global__ __launch_bounds__(256) void attn_split(
    const float* __restrict__ qkvf, const float* __restrict__ kcache,
    const float* __restrict__ vcache, const int* __restrict__ btab,
    const int* __restrict__ ctxlen,
    float* __restrict__ part_o,   // [B*HKV*SPLITS][4][128]
    float* __restrict__ part_ml)  // [B*HKV*SPLITS][4][2]
{
  const int bid = blockIdx.x;
  const int s   = bid & (SPLITS - 1);
  const int bh  = bid >> 3;
  const int b = bh >> 3, h = bh & 7;
  const int ctx   = ctxlen[b];
  const int chunk = (ctx + SPLITS - 1) / SPLITS;   // <= 128
  const int t0 = s * chunk;
  const int t1 = min(ctx, t0 + chunk);
  const int n  = t1 - t0;
  const int last = ctx - 1;

  const int tid  = threadIdx.x;
  const int half = tid >> 5;     // 0..7
  const int d4   = tid & 31;

  __shared__ float sc[4][128];
  __shared__ float oacc[8][4][128];
  __shared__ float red[4][2];    // m, l per group-head

  float4 qf[4];
  #pragma unroll
  for (int g = 0; g < 4; ++g)
    qf[g] = *(const float4*)(qkvf + (size_t)(b * 32 + h * 4 + g) * 128 + d4 * 4);

  const float* knew = qkvf + 262144 + (size_t)(b * 8 + h) * 128;
  const float* vnew = qkvf + 327680 + (size_t)(b * 8 + h) * 128;

  // ---- pass 1: scores for this chunk
  for (int t = t0 + half; t < t1; t += 8) {
    const float* kp;
    if (t == last) kp = knew;
    else {
      int slot = btab[b * MAXB_ + (t >> 4)] * BS_ + (t & 15);
      kp = kcache + ((size_t)slot * HKV_ + h) * D_;
    }
    float4 kv = *(const float4*)(kp + d4 * 4);
    float p0 = qf[0].x * kv.x + qf[0].y * kv.y + qf[0].z * kv.z + qf[0].w * kv.w;
    float p1 = qf[1].x * kv.x + qf[1].y * kv.y + qf[1].z * kv.z + qf[1].w * kv.w;
    float p2 = qf[2].x * kv.x + qf[2].y * kv.y + qf[2].z * kv.z + qf[2].w * kv.w;
    float p3 = qf[3].x * kv.x + qf[3].y * kv.y + qf[3].z * kv.z + qf[3].w * kv.w;
    #pragma unroll
    for (int m = 16; m >= 1; m >>= 1) {
      p0 += __shfl_xor(p0, m);
      p1 += __shfl_xor(p1, m);
      p2 += __shfl_xor(p2, m);
      p3 += __shfl_xor(p3, m);
    }
    if (d4 == 0) {
      int i = t - t0;
      sc[0][i] = p0; sc[1][i] = p1; sc[2][i] = p2; sc[3][i] = p3;
    }
  }
  __syncthreads();

  // ---- partial softmax: wave w handles group-head g = w
  {
    const int w = tid >> 6, l = tid & 63;
    float mx = -1e30f;
    for (int i = l; i < n; i += 64) mx = fmaxf(mx, sc[w][i]);
    #pragma unroll
    for (int m = 32; m >= 1; m >>= 1) mx = fmaxf(mx, __shfl_xor(mx, m));
    float lsum = 0.f;
    for (int i = l; i < n; i += 64) {
      float p = __expf(sc[w][i] - mx);
      sc[w][i] = p;
      lsum += p;
    }
    #pragma unroll
    for (int m = 32; m >= 1; m >>= 1) lsum += __shfl_xor(lsum, m);
    if (l == 0) { red[w][0] = mx; red[w][1] = lsum; }
  }
  __syncthreads();

  // ---- pass 2: sum p*V (unnormalized)
  float acc[4][4] = {{0.f}};
  for (int t = t0 + half; t < t1; t += 8) {
    const float* vp;
    if (t == last) vp = vnew;
    else {
      int slot = btab[b * MAXB_ + (t >> 4)] * BS_ + (t & 15);
      vp = vcache + ((size_t)slot * HKV_ + h) * D_;
    }
    float4 vv = *(const float4*)(vp + d4 * 4);
    int i = t - t0;
    #pragma unroll
    for (int g = 0; g < 4; ++g) {
      float p = sc[g][i];
      acc[g][0] += p * vv.x; acc[g][1] += p * vv.y;
      acc[g][2] += p * vv.z; acc[g][3] += p * vv.w;
    }
  }
  #pragma unroll
  for (int g = 0; g < 4; ++g)
    #pragma unroll
    for (int j = 0; j < 4; ++j)
      oacc[half][g][d4 * 4 + j] = acc[g][j];
  __syncthreads();

  for (int idx = tid; idx < 512; idx += 256) {
    int g = idx >> 7, d = idx & 127;
    float v = 0.f;
    #pragma unroll
    for (int hh = 0; hh < 8; ++hh) v += oacc[hh][g][d];
    part_o[(size_t)bid * 512 + idx] = v;
  }
  if (tid < 8) part_ml[(size_t)bid * 8 + tid] = red[tid >> 1][tid & 1];
}

// ---------------------------------------------------------------------------
// Combine split partials: out = sum_s exp(m_s-M) o_s / sum_s exp(m_s-M) l_s
// ---------------------------------------------------------------------------
__global__ __launch_bounds__(256) void attn_combine(
    const float* __restrict__ part_o, const float* __restrict__ part_ml,
    float* __restrict__ attn_out)
{
  const int bh = blockIdx.x;            // 0..511
  const int tid = threadIdx.x;

  __shared__ float Sg[SPLITS][4];
  __shared__ float Dg[4];

  if (tid < 32) {                       // lane = s*4+g
    int s = tid >> 2, g = tid & 3;
    float m = part_ml[((size_t)bh * SPLITS + s) * 8 + g * 2];
    float l = part_ml[((size_t)bh * SPLITS + s) * 8 + g * 2 + 1];
    float M = m;
    #pragma unroll
    for (int k = 4; k <= 16; k <<= 1) M = fmaxf(M, __shfl_xor(M, k));
    float scl = __expf(m - M);
    float dl = l * scl;
    #pragma unroll
    for (int k = 4; k <= 16; k <<= 1) dl += __shfl_xor(dl, k);
    Sg[s][g] = scl;
    if (s == 0) Dg[g] = dl;
  }
  __syncthreads();

  for (int idx = tid; idx < 512; idx += 256) {
    int g = idx >> 7;
    float num = 0.f;
    #pragma unroll
    for (int s = 0; s < SPLITS; ++s)
      num += Sg[s][g] * part_o[((size_t)bh * SPLITS + s) * 512 + idx];
    attn_out[(size_t)bh * 512 + idx] = num / Dg[g];
  }
}

// ---------------------------------------------------------------------------
// part3 is batch-major: [ks][batch][4096 rows] -> fully coalesced both sides
// ---------------------------------------------------------------------------
__global__ __launch_bounds__(256) void reduce_out(
    const float* __restrict__ part, float* __restrict__ out)
{
  int o  = blockIdx.x * 256 + threadIdx.x;  // 0..262143
  int bb = o >> 12, i = o & 4095;
  float s = 0.f;
  #pragma unroll
  for (int ks = 0; ks < KSPLIT; ++ks)
    s += part[((size_t)ks * 64 + bb) * O_ROWS + i];
  out[o] = s;
}

// ---------------------------------------------------------------------------
extern "C" void kernel_launch(void* const* d_in, const int* in_sizes, int n_in,
                              void* d_out, int out_size, void* d_ws, size_t ws_size,
                              hipStream_t stream)
{
  (void)in_sizes; (void)n_in; (void)out_size; (void)ws_size;
  const float* hidden    = (const float*)d_in[0];
  const int*   positions = (const int*)d_in[1];
  const float* cosT      = (const float*)d_in[2];
  const float* sinT      = (const float*)d_in[3];
  const float* kcache    = (const float*)d_in[4];
  const float* vcache    = (const float*)d_in[5];
  const int*   btab      = (const int*)d_in[7];
  const int*   ctx       = (const int*)d_in[8];
  const float* Wq        = (const float*)d_in[9];
  const float* Wk        = (const float*)d_in[10];
  const float* Wv        = (const float*)d_in[11];
  const float* Wo        = (const float*)d_in[12];
  float* out = (float*)d_out;

  float* ws     = (float*)d_ws;
  float* part1  = ws;
  float* qkvf   = part1 + PART1_SZ;
  float* attn_o = qkvf + QKVF_SZ;
  float* part3  = attn_o + ATTN_SZ;
  // attention partials overlay part1 (dead after reduce_rope)
  float* part_o  = part1;                                  // 4096*512 floats
  float* part_ml = part1 + (size_t)B_ * HKV_ * SPLITS * 512;  // 4096*8 floats

  gemm_part<<<dim3(QKV_ROWS / RPB, KSPLIT), 256, 0, stream>>>(
      hidden, Wq, Wk, Wv, 4096, 5120, QKV_ROWS, 0, part1);
  reduce_rope<<<768, 256, 0, stream>>>(part1, cosT, sinT, positions, qkvf);
  attn_split<<<B_ * HKV_ * SPLITS, 256, 0, stream>>>(
      qkvf, kcache, vcache, btab, ctx, part_o, part_ml);
  attn_combine<<<B_ * HKV_, 256, 0, stream>>>(part_o, part_ml, attn_o);
  gemm_part<<<dim3(O_ROWS / RPB, KSPLIT), 256, 0, stream>>>(
      attn_o, Wo, Wo, Wo, O_ROWS, O_ROWS, O_ROWS, 1, part3);
  reduce_out<<<1024, 256, 0, stream>>>(part3, out);
}